// Round 16
// baseline (83.540 us; speedup 1.0000x reference)
//
#include <hip/hip_runtime.h>
#include <stdint.h>

// CorrelationLayer via MFMA Gram tiles — 512-thr blocks for 2-block/CU overlap.
// out[j*7+i, h, w] = sum_c x[c,h,w] * y[c,h+j-3,w+i-3], zero-padded.
//
// R16 theory: R15 (66us, spill-free) runs 1024-thr blocks at 64 arch + ~64
// acc VGPRs = 128 total -> 16-wave/CU tier -> exactly ONE resident block/CU:
// zero inter-block overlap, staging latency fully exposed (all pipes <=10%).
// acc+af (72 regs) is irreducible, so halve the BLOCK instead: 512 thr /
// 8 waves = 4 output rows x 32-px slab, NROW=10, LDS 32KB -> 2 blocks/CU
// at the same 128-reg tier. Block A's stage phase overlaps block B's compute.
// Halo redundancy 2.5x (vs R14 1.75x, R7 7x) — slightly more traffic traded
// for restored concurrency.
// All math byte-identical to R15: col-pair staging (8x float2 -> pkbf ->
// 2x b128 w/ kb-XOR swizzle kb^((c2>>2)&3), read-inverted g^((col>>3)&3));
// A/B frag lane {m|n}=l&15, k=(l>>4)*8+e; C/D col=lane&15,row=(lane>>4)*4+reg;
// extraction slab 16x34 f32, i=g / g+4 (g<3).
// Grid 96 hg x 16 slabs = 1536; XCD k owns hg [12k,12k+12), slab-fastest
// (one hg's 16 slabs share 10 y-rows = 2.6MB, L2-resident per XCD).

typedef __attribute__((ext_vector_type(8))) short short8;
typedef __attribute__((ext_vector_type(4))) float floatx4;

constexpr int C = 128;
constexpr int H = 384;
constexpr int W = 512;
constexpr int HW = H * W;

constexpr int NROW = 10;              // rows h0-3 .. h0+6
constexpr int NCOL = 40;              // LDS col 0 = abs ws_blk - 4
constexpr int KP   = 40;              // bf16 per col (32 k + 8 pad) = 80 B
constexpr int ROWB = NCOL * KP * 2;   // 3200 B per row
constexpr int BUFE = NROW * NCOL * KP;        // 16000 bf16 elems (32 KB)
constexpr int NUNIT = NROW * 4 * (NCOL / 2);  // 800 staging units

__device__ __forceinline__ uint32_t pkbf(float a, float b) {
  uint32_t ua = (__float_as_uint(a) + 0x8000u) >> 16;
  uint32_t ub = (__float_as_uint(b) + 0x8000u) & 0xffff0000u;
  return ua | ub;
}

union S8U { uint32_t u[4]; short8 s; };

// stage one unit: (row, kb, col-pair) = 8 k-planes x 2 cols; inline
// load -> pack -> swizzled ds_write (no regs live across compute phases).
__device__ __forceinline__ void stage_unit(const float* __restrict__ y,
                                           uint16_t* __restrict__ buf,
                                           int kc, int h0, int ws_blk, int u) {
  const int c2  = u % 20;
  const int kb  = (u / 20) & 3;
  const int row = u / 80;                    // 0..9
  const int r_abs = h0 - 3 + row;
  const int cb    = ws_blk - 4 + 2 * c2;     // even -> no pair straddle
  const bool val = (r_abs >= 0) & (r_abs < H) & (cb >= 0) & (cb <= W - 2);
  const int r  = r_abs < 0 ? 0 : (r_abs >= H ? H - 1 : r_abs);
  const int cc = cb < 0 ? 0 : (cb > W - 2 ? W - 2 : cb);
  const float* src = y + (size_t)(kc * 32 + kb * 8) * HW + (size_t)r * W + cc;
  float2 f[8];
#pragma unroll
  for (int e = 0; e < 8; ++e)
    f[e] = *reinterpret_cast<const float2*>(src + (size_t)e * HW);
  uint4 v0, v1;
  v0.x = pkbf(f[0].x, f[1].x); v0.y = pkbf(f[2].x, f[3].x);
  v0.z = pkbf(f[4].x, f[5].x); v0.w = pkbf(f[6].x, f[7].x);
  v1.x = pkbf(f[0].y, f[1].y); v1.y = pkbf(f[2].y, f[3].y);
  v1.z = pkbf(f[4].y, f[5].y); v1.w = pkbf(f[6].y, f[7].y);
  if (!val) { v0 = make_uint4(0, 0, 0, 0); v1 = make_uint4(0, 0, 0, 0); }
  const int kbs  = kb ^ ((c2 >> 2) & 3);     // bank swizzle (16B granule)
  const int ldso = (row * NCOL + 2 * c2) * KP + kbs * 8;
  *reinterpret_cast<uint4*>(&buf[ldso])      = v0;
  *reinterpret_cast<uint4*>(&buf[ldso + KP]) = v1;   // same quad -> same swz
}

__global__ __launch_bounds__(512, 2)
void corr_mfma(const float* __restrict__ x, const float* __restrict__ y,
               float* __restrict__ out) {
  __shared__ uint16_t ys[BUFE];              // 32000 B

  const int bid  = blockIdx.x;
  const int xcd  = bid & 7;
  const int idx  = bid >> 3;                 // 0..191
  const int hg   = xcd * 12 + (idx >> 4);    // 0..95
  const int slab = idx & 15;
  const int h0     = hg * 4;
  const int ws_blk = slab * 32;
  const int tid  = threadIdx.x;
  const int wv   = tid >> 6;                 // 0..7
  const int lane = tid & 63;
  const int m  = lane & 15;
  const int g  = lane >> 4;
  const int dh = wv >> 1;                    // 0..3
  const int ww = wv & 1;                     // 0..1
  const int h  = h0 + dh;
  const int ws = ws_blk + ww * 16;

  const bool has2 = (tid < NUNIT - 512);     // 288 threads own a 2nd unit

  floatx4 acc[7][2];
#pragma unroll
  for (int j = 0; j < 7; ++j) {
    acc[j][0] = (floatx4){0.f, 0.f, 0.f, 0.f};
    acc[j][1] = (floatx4){0.f, 0.f, 0.f, 0.f};
  }

  // ---- A fragments preload: af[kc], A[m][k] = x[k][h][ws+m], k=g*8+e ----
  short8 af[4];
  {
    const float* xb = x + (size_t)(g * 8) * HW + (size_t)h * W + (ws + m);
#pragma unroll
    for (int kc = 0; kc < 4; ++kc) {
      float f[8];
#pragma unroll
      for (int e = 0; e < 8; ++e) f[e] = xb[(size_t)(kc * 32 + e) * HW];
      S8U s;
      s.u[0] = pkbf(f[0], f[1]);
      s.u[1] = pkbf(f[2], f[3]);
      s.u[2] = pkbf(f[4], f[5]);
      s.u[3] = pkbf(f[6], f[7]);
      af[kc] = s.s;
    }
  }

  // per-lane b128 read byte-offsets within a row slab (swizzle-inverted)
  const int col0 = ww * 16 + m + 1;          // abs ws-3+m
  int col1 = col0 + 16;                      // tile1; clamp unused lanes
  if (col1 > NCOL - 1) col1 = NCOL - 1;
  const int fb0 = col0 * (KP * 2) + (g ^ ((col0 >> 3) & 3)) * 16;
  const int fb1 = col1 * (KP * 2) + (g ^ ((col1 >> 3) & 3)) * 16;

  // ---- main loop: plain stage -> barrier -> compute -> barrier ----
#pragma unroll
  for (int kc = 0; kc < 4; ++kc) {
    if (kc) __syncthreads();                 // reads of previous chunk done
    stage_unit(y, ys, kc, h0, ws_blk, tid);
    if (has2) stage_unit(y, ys, kc, h0, ws_blk, 512 + tid);
    __syncthreads();

    // compute chunk kc: B row = dh + j
#pragma unroll
    for (int j = 0; j < 7; ++j) {
      const uint8_t* rb =
          reinterpret_cast<const uint8_t*>(ys) + (dh + j) * ROWB;
      const short8 b0 = *reinterpret_cast<const short8*>(rb + fb0);
      const short8 b1 = *reinterpret_cast<const short8*>(rb + fb1);
      acc[j][0] = __builtin_amdgcn_mfma_f32_16x16x32_bf16(af[kc], b0, acc[j][0], 0, 0, 0);
      acc[j][1] = __builtin_amdgcn_mfma_f32_16x16x32_bf16(af[kc], b1, acc[j][1], 0, 0, 0);
    }
  }

  // ---- extraction: per-wave 16x34 f32 slab (reuses ys; 8*2176B fits) ----
  __syncthreads();
  float* slabp = reinterpret_cast<float*>(ys) + wv * 544;
#pragma unroll
  for (int j = 0; j < 7; ++j) {
#pragma unroll
    for (int q = 0; q < 4; ++q) {
      slabp[(g * 4 + q) * 34 + m]      = acc[j][0][q];   // cols 0..15
      slabp[(g * 4 + q) * 34 + 16 + m] = acc[j][1][q];   // cols 16..31
    }
    const float vo0 = slabp[m * 34 + m + g];             // i = g
    const float vo1 = slabp[m * 34 + m + g + 4];         // i = g+4 (g<3)
    float* ob = out + (size_t)(j * 7 + g) * HW + (size_t)h * W + (ws + m);
    *ob = vo0;
    if (g < 3) ob[(size_t)4 * HW] = vo1;
  }
}

extern "C" void kernel_launch(void* const* d_in, const int* in_sizes, int n_in,
                              void* d_out, int out_size, void* d_ws, size_t ws_size,
                              hipStream_t stream) {
  const float* x = (const float*)d_in[0];
  const float* y = (const float*)d_in[1];
  float* out = (float*)d_out;
  corr_mfma<<<dim3(96 * 16), dim3(512), 0, stream>>>(x, y, out);
}

// Round 17
// 69.487 us; speedup vs baseline: 1.2022x; 1.2022x over previous
//
#include <hip/hip_runtime.h>
#include <stdint.h>

// CorrelationLayer via MFMA Gram tiles — mega-stage: all K staged, ONE barrier.
// out[j*7+i, h, w] = sum_c x[c,h,w] * y[c,h+j-3,w+i-3], zero-padded.
//
// R17 theory: R14-R16 accounting shows ~50% of runtime is pure wait: the
// stage->barrier->compute->barrier x4 structure exposes staging latency 4x
// per block with 1 block/CU (no cross-block cover; R16 proved 2 blocks/CU
// is unreachable at acc+af=72 regs/wave). Fix: stage ALL 128 channels into
// 4 chunk-buffers (R15's layout per buffer, byte-identical: [12 rows][40
// cols][k32 pad40] bf16, kb-XOR swizzle kb^((c2>>2)&3), read-inverted
// g^((col>>3)&3)), then ONE barrier, then all 4x14 MFMAs uninterrupted.
// Barriers/block 8 -> 2; each thread issues 5 independent staging units
// (40 loads) -> deep memory-level parallelism, single latency exposure.
// Block: 768 thr / 12 waves = 6 output rows x 32-px slab; wave (dh 0..5,
// ww 0..1); NROW=12 covers B rows dh+j in 0..11. LDS 4x38400 = 153.6 KB.
// 3 waves/SIMD tier (<=170 regs) -> no spill pressure (R16: 4-tier squeeze).
// Math byte-identical to R15: A/B frag lane {m|n}=l&15, k=(l>>4)*8+e;
// C/D col=lane&15, row=(lane>>4)*4+reg; extraction slab 16x34, i=g / g+4.
// Grid 64 hg x 16 slabs = 1024; XCD k owns hg [8k,8k+8), slab-fastest.

typedef __attribute__((ext_vector_type(8))) short short8;
typedef __attribute__((ext_vector_type(4))) float floatx4;

constexpr int C = 128;
constexpr int H = 384;
constexpr int W = 512;
constexpr int HW = H * W;

constexpr int NROW = 12;              // rows h0-3 .. h0+8
constexpr int NCOL = 40;              // LDS col 0 = abs ws_blk - 4
constexpr int KP   = 40;              // bf16 per col (32 k + 8 pad) = 80 B
constexpr int ROWB = NCOL * KP * 2;   // 3200 B per row
constexpr int BUFE = NROW * NCOL * KP;        // 19200 bf16 elems (38.4 KB)
constexpr int NUNIT = NROW * 4 * (NCOL / 2);  // 960 staging units per chunk

__device__ __forceinline__ uint32_t pkbf(float a, float b) {
  uint32_t ua = (__float_as_uint(a) + 0x8000u) >> 16;
  uint32_t ub = (__float_as_uint(b) + 0x8000u) & 0xffff0000u;
  return ua | ub;
}

union S8U { uint32_t u[4]; short8 s; };

// stage one unit: (row, kb, col-pair) = 8 k-planes x 2 cols; inline
// load -> pack -> swizzled ds_write.
__device__ __forceinline__ void stage_unit(const float* __restrict__ y,
                                           uint16_t* __restrict__ buf,
                                           int kc, int h0, int ws_blk, int u) {
  const int c2  = u % 20;
  const int kb  = (u / 20) & 3;
  const int row = u / 80;                    // 0..11
  const int r_abs = h0 - 3 + row;
  const int cb    = ws_blk - 4 + 2 * c2;     // even -> no pair straddle
  const bool val = (r_abs >= 0) & (r_abs < H) & (cb >= 0) & (cb <= W - 2);
  const int r  = r_abs < 0 ? 0 : (r_abs >= H ? H - 1 : r_abs);
  const int cc = cb < 0 ? 0 : (cb > W - 2 ? W - 2 : cb);
  const float* src = y + (size_t)(kc * 32 + kb * 8) * HW + (size_t)r * W + cc;
  float2 f[8];
#pragma unroll
  for (int e = 0; e < 8; ++e)
    f[e] = *reinterpret_cast<const float2*>(src + (size_t)e * HW);
  uint4 v0, v1;
  v0.x = pkbf(f[0].x, f[1].x); v0.y = pkbf(f[2].x, f[3].x);
  v0.z = pkbf(f[4].x, f[5].x); v0.w = pkbf(f[6].x, f[7].x);
  v1.x = pkbf(f[0].y, f[1].y); v1.y = pkbf(f[2].y, f[3].y);
  v1.z = pkbf(f[4].y, f[5].y); v1.w = pkbf(f[6].y, f[7].y);
  if (!val) { v0 = make_uint4(0, 0, 0, 0); v1 = make_uint4(0, 0, 0, 0); }
  const int kbs  = kb ^ ((c2 >> 2) & 3);     // bank swizzle (16B granule)
  const int ldso = (row * NCOL + 2 * c2) * KP + kbs * 8;
  *reinterpret_cast<uint4*>(&buf[ldso])      = v0;
  *reinterpret_cast<uint4*>(&buf[ldso + KP]) = v1;   // same quad -> same swz
}

__global__ __launch_bounds__(768, 3)
void corr_mfma(const float* __restrict__ x, const float* __restrict__ y,
               float* __restrict__ out) {
  __shared__ uint16_t ys[4][BUFE];           // 153600 B

  const int bid  = blockIdx.x;
  const int xcd  = bid & 7;
  const int idx  = bid >> 3;                 // 0..127
  const int hg   = xcd * 8 + (idx >> 4);     // 0..63
  const int slab = idx & 15;
  const int h0     = hg * 6;
  const int ws_blk = slab * 32;
  const int tid  = threadIdx.x;
  const int wv   = tid >> 6;                 // 0..11
  const int lane = tid & 63;
  const int m  = lane & 15;
  const int g  = lane >> 4;
  const int dh = wv >> 1;                    // 0..5
  const int ww = wv & 1;                     // 0..1
  const int h  = h0 + dh;
  const int ws = ws_blk + ww * 16;

  const bool has2 = (tid < NUNIT - 768);     // 192 threads own a 2nd unit

  floatx4 acc[7][2];
#pragma unroll
  for (int j = 0; j < 7; ++j) {
    acc[j][0] = (floatx4){0.f, 0.f, 0.f, 0.f};
    acc[j][1] = (floatx4){0.f, 0.f, 0.f, 0.f};
  }

  // ---- stage ALL 4 chunks (5 independent units/thread), no barriers ----
#pragma unroll
  for (int kc = 0; kc < 4; ++kc) {
    stage_unit(y, ys[kc], kc, h0, ws_blk, tid);
    if (has2) stage_unit(y, ys[kc], kc, h0, ws_blk, 768 + tid);
  }

  // ---- A fragments preload: af[kc], A[m][k] = x[k][h][ws+m], k=g*8+e ----
  short8 af[4];
  {
    const float* xb = x + (size_t)(g * 8) * HW + (size_t)h * W + (ws + m);
#pragma unroll
    for (int kc = 0; kc < 4; ++kc) {
      float f[8];
#pragma unroll
      for (int e = 0; e < 8; ++e) f[e] = xb[(size_t)(kc * 32 + e) * HW];
      S8U s;
      s.u[0] = pkbf(f[0], f[1]);
      s.u[1] = pkbf(f[2], f[3]);
      s.u[2] = pkbf(f[4], f[5]);
      s.u[3] = pkbf(f[6], f[7]);
      af[kc] = s.s;
    }
  }

  // per-lane b128 read byte-offsets within a row slab (swizzle-inverted)
  const int col0 = ww * 16 + m + 1;          // abs ws-3+m
  int col1 = col0 + 16;                      // tile1; clamp unused lanes
  if (col1 > NCOL - 1) col1 = NCOL - 1;
  const int fb0 = col0 * (KP * 2) + (g ^ ((col0 >> 3) & 3)) * 16;
  const int fb1 = col1 * (KP * 2) + (g ^ ((col1 >> 3) & 3)) * 16;

  __syncthreads();                           // the ONE staging barrier

  // ---- compute: all 4 chunks x 7 j, uninterrupted ----
#pragma unroll
  for (int kc = 0; kc < 4; ++kc) {
#pragma unroll
    for (int j = 0; j < 7; ++j) {
      const uint8_t* rb =
          reinterpret_cast<const uint8_t*>(&ys[kc][0]) + (dh + j) * ROWB;
      const short8 b0 = *reinterpret_cast<const short8*>(rb + fb0);
      const short8 b1 = *reinterpret_cast<const short8*>(rb + fb1);
      acc[j][0] = __builtin_amdgcn_mfma_f32_16x16x32_bf16(af[kc], b0, acc[j][0], 0, 0, 0);
      acc[j][1] = __builtin_amdgcn_mfma_f32_16x16x32_bf16(af[kc], b1, acc[j][1], 0, 0, 0);
    }
  }

  // ---- extraction: per-wave 16x34 f32 slab (reuses ys[0]; 12*2176B fits) ----
  __syncthreads();
  float* slabp = reinterpret_cast<float*>(&ys[0][0]) + wv * 544;
#pragma unroll
  for (int j = 0; j < 7; ++j) {
#pragma unroll
    for (int q = 0; q < 4; ++q) {
      slabp[(g * 4 + q) * 34 + m]      = acc[j][0][q];   // cols 0..15
      slabp[(g * 4 + q) * 34 + 16 + m] = acc[j][1][q];   // cols 16..31
    }
    const float vo0 = slabp[m * 34 + m + g];             // i = g
    const float vo1 = slabp[m * 34 + m + g + 4];         // i = g+4 (g<3)
    float* ob = out + (size_t)(j * 7 + g) * HW + (size_t)h * W + (ws + m);
    *ob = vo0;
    if (g < 3) ob[(size_t)4 * HW] = vo1;
  }
}

extern "C" void kernel_launch(void* const* d_in, const int* in_sizes, int n_in,
                              void* d_out, int out_size, void* d_ws, size_t ws_size,
                              hipStream_t stream) {
  const float* x = (const float*)d_in[0];
  const float* y = (const float*)d_in[1];
  float* out = (float*)d_out;
  corr_mfma<<<dim3(64 * 16), dim3(768), 0, stream>>>(x, y, out);
}

// Round 18
// 59.068 us; speedup vs baseline: 1.4143x; 1.1764x over previous
//
#include <hip/hip_runtime.h>
#include <stdint.h>

// CorrelationLayer via MFMA Gram tiles — 2 blocks/CU, for real this time.
// out[j*7+i, h, w] = sum_c x[c,h,w] * y[c,h+j-3,w+i-3], zero-padded.
//
// R18 = R16 (512 thr / 8 waves = 4 output rows x 32-px slab, NROW=10,
// LDS 32KB) with the 4-register miss fixed:
//  - __launch_bounds__(512, 4): force the <=128-combined-reg tier so TWO
//    8-wave blocks co-reside per CU (R16: 68 arch + 64 acc = 132 -> 1 block,
//    occupancy 22%, dur 83us).
//  - af loaded per-chunk (short8, 4 regs) instead of af[4] preload (16):
//    x slice is 16KB/block -> L1-resident after chunk 0; load issues in the
//    staging phase. Live state: acc 56 + af 4 + addr ~20 + burst ~24 -> ~104.
// Cross-block overlap: two resident blocks dephase naturally; block A's
// staging (memory latency) hides under block B's compute (MFMA+ds_read).
// R17 falsified the barrier-count theory (1 barrier = same dur), so phase
// structure stays simple: stage -> barrier -> compute -> barrier, 4 chunks.
// All math byte-identical to R15/R16: col-pair staging (8x float2 -> pkbf ->
// 2x b128, kb-XOR swizzle kb^((c2>>2)&3), read-inverted g^((col>>3)&3));
// A/B frag lane {m|n}=l&15, k=(l>>4)*8+e; C/D col=lane&15,row=(lane>>4)*4+reg;
// extraction slab 16x34 f32, i=g / g+4 (g<3).
// Grid 96 hg x 16 slabs = 1536; XCD k owns hg [12k,12k+12), slab-fastest.

typedef __attribute__((ext_vector_type(8))) short short8;
typedef __attribute__((ext_vector_type(4))) float floatx4;

constexpr int C = 128;
constexpr int H = 384;
constexpr int W = 512;
constexpr int HW = H * W;

constexpr int NROW = 10;              // rows h0-3 .. h0+6
constexpr int NCOL = 40;              // LDS col 0 = abs ws_blk - 4
constexpr int KP   = 40;              // bf16 per col (32 k + 8 pad) = 80 B
constexpr int ROWB = NCOL * KP * 2;   // 3200 B per row
constexpr int BUFE = NROW * NCOL * KP;        // 16000 bf16 elems (32 KB)
constexpr int NUNIT = NROW * 4 * (NCOL / 2);  // 800 staging units

__device__ __forceinline__ uint32_t pkbf(float a, float b) {
  uint32_t ua = (__float_as_uint(a) + 0x8000u) >> 16;
  uint32_t ub = (__float_as_uint(b) + 0x8000u) & 0xffff0000u;
  return ua | ub;
}

union S8U { uint32_t u[4]; short8 s; };

// stage one unit: (row, kb, col-pair) = 8 k-planes x 2 cols; inline
// load -> pack -> swizzled ds_write (nothing lives across compute phases).
__device__ __forceinline__ void stage_unit(const float* __restrict__ y,
                                           uint16_t* __restrict__ buf,
                                           int kc, int h0, int ws_blk, int u) {
  const int c2  = u % 20;
  const int kb  = (u / 20) & 3;
  const int row = u / 80;                    // 0..9
  const int r_abs = h0 - 3 + row;
  const int cb    = ws_blk - 4 + 2 * c2;     // even -> no pair straddle
  const bool val = (r_abs >= 0) & (r_abs < H) & (cb >= 0) & (cb <= W - 2);
  const int r  = r_abs < 0 ? 0 : (r_abs >= H ? H - 1 : r_abs);
  const int cc = cb < 0 ? 0 : (cb > W - 2 ? W - 2 : cb);
  const float* src = y + (size_t)(kc * 32 + kb * 8) * HW + (size_t)r * W + cc;
  float2 f[8];
#pragma unroll
  for (int e = 0; e < 8; ++e)
    f[e] = *reinterpret_cast<const float2*>(src + (size_t)e * HW);
  uint4 v0, v1;
  v0.x = pkbf(f[0].x, f[1].x); v0.y = pkbf(f[2].x, f[3].x);
  v0.z = pkbf(f[4].x, f[5].x); v0.w = pkbf(f[6].x, f[7].x);
  v1.x = pkbf(f[0].y, f[1].y); v1.y = pkbf(f[2].y, f[3].y);
  v1.z = pkbf(f[4].y, f[5].y); v1.w = pkbf(f[6].y, f[7].y);
  if (!val) { v0 = make_uint4(0, 0, 0, 0); v1 = make_uint4(0, 0, 0, 0); }
  const int kbs  = kb ^ ((c2 >> 2) & 3);     // bank swizzle (16B granule)
  const int ldso = (row * NCOL + 2 * c2) * KP + kbs * 8;
  *reinterpret_cast<uint4*>(&buf[ldso])      = v0;
  *reinterpret_cast<uint4*>(&buf[ldso + KP]) = v1;   // same quad -> same swz
}

__global__ __launch_bounds__(512, 4)
void corr_mfma(const float* __restrict__ x, const float* __restrict__ y,
               float* __restrict__ out) {
  __shared__ uint16_t ys[BUFE];              // 32000 B

  const int bid  = blockIdx.x;
  const int xcd  = bid & 7;
  const int idx  = bid >> 3;                 // 0..191
  const int hg   = xcd * 12 + (idx >> 4);    // 0..95
  const int slab = idx & 15;
  const int h0     = hg * 4;
  const int ws_blk = slab * 32;
  const int tid  = threadIdx.x;
  const int wv   = tid >> 6;                 // 0..7
  const int lane = tid & 63;
  const int m  = lane & 15;
  const int g  = lane >> 4;
  const int dh = wv >> 1;                    // 0..3
  const int ww = wv & 1;                     // 0..1
  const int h  = h0 + dh;
  const int ws = ws_blk + ww * 16;

  const bool has2 = (tid < NUNIT - 512);     // 288 threads own a 2nd unit

  floatx4 acc[7][2];
#pragma unroll
  for (int j = 0; j < 7; ++j) {
    acc[j][0] = (floatx4){0.f, 0.f, 0.f, 0.f};
    acc[j][1] = (floatx4){0.f, 0.f, 0.f, 0.f};
  }

  // per-lane b128 read byte-offsets within a row slab (swizzle-inverted)
  const int col0 = ww * 16 + m + 1;          // abs ws-3+m
  int col1 = col0 + 16;                      // tile1; clamp unused lanes
  if (col1 > NCOL - 1) col1 = NCOL - 1;
  const int fb0 = col0 * (KP * 2) + (g ^ ((col0 >> 3) & 3)) * 16;
  const int fb1 = col1 * (KP * 2) + (g ^ ((col1 >> 3) & 3)) * 16;

  const float* xb = x + (size_t)(g * 8) * HW + (size_t)h * W + (ws + m);

  // ---- main loop: stage -> (af load) -> barrier -> compute ----
#pragma unroll
  for (int kc = 0; kc < 4; ++kc) {
    if (kc) __syncthreads();                 // reads of previous chunk done
    stage_unit(y, ys, kc, h0, ws_blk, tid);
    if (has2) stage_unit(y, ys, kc, h0, ws_blk, 512 + tid);

    // A fragment for THIS chunk (x slice is L1-resident after chunk 0;
    // issued during the staging phase, consumed after the barrier).
    short8 af;
    {
      float f[8];
#pragma unroll
      for (int e = 0; e < 8; ++e)
        f[e] = xb[(size_t)(kc * 32 + e) * HW];
      S8U s;
      s.u[0] = pkbf(f[0], f[1]);
      s.u[1] = pkbf(f[2], f[3]);
      s.u[2] = pkbf(f[4], f[5]);
      s.u[3] = pkbf(f[6], f[7]);
      af = s.s;
    }
    __syncthreads();

    // compute chunk kc: B row = dh + j
#pragma unroll
    for (int j = 0; j < 7; ++j) {
      const uint8_t* rb =
          reinterpret_cast<const uint8_t*>(ys) + (dh + j) * ROWB;
      const short8 b0 = *reinterpret_cast<const short8*>(rb + fb0);
      const short8 b1 = *reinterpret_cast<const short8*>(rb + fb1);
      acc[j][0] = __builtin_amdgcn_mfma_f32_16x16x32_bf16(af, b0, acc[j][0], 0, 0, 0);
      acc[j][1] = __builtin_amdgcn_mfma_f32_16x16x32_bf16(af, b1, acc[j][1], 0, 0, 0);
    }
  }

  // ---- extraction: per-wave 16x34 f32 slab (reuses ys; 8*2176B fits) ----
  __syncthreads();
  float* slabp = reinterpret_cast<float*>(ys) + wv * 544;
#pragma unroll
  for (int j = 0; j < 7; ++j) {
#pragma unroll
    for (int q = 0; q < 4; ++q) {
      slabp[(g * 4 + q) * 34 + m]      = acc[j][0][q];   // cols 0..15
      slabp[(g * 4 + q) * 34 + 16 + m] = acc[j][1][q];   // cols 16..31
    }
    const float vo0 = slabp[m * 34 + m + g];             // i = g
    const float vo1 = slabp[m * 34 + m + g + 4];         // i = g+4 (g<3)
    float* ob = out + (size_t)(j * 7 + g) * HW + (size_t)h * W + (ws + m);
    *ob = vo0;
    if (g < 3) ob[(size_t)4 * HW] = vo1;
  }
}

extern "C" void kernel_launch(void* const* d_in, const int* in_sizes, int n_in,
                              void* d_out, int out_size, void* d_ws, size_t ws_size,
                              hipStream_t stream) {
  const float* x = (const float*)d_in[0];
  const float* y = (const float*)d_in[1];
  float* out = (float*)d_out;
  corr_mfma<<<dim3(96 * 16), dim3(512), 0, stream>>>(x, y, out);
}